// Round 2
// baseline (523.023 us; speedup 1.0000x reference)
//
#include <hip/hip_runtime.h>
#include <math.h>

#define N_ANCHORS 2048
#define BLOCK 256
#define THRESH 0.3f
#define OVERLAP 0.5f

__global__ __launch_bounds__(BLOCK) void det_kernel(
    const float* __restrict__ loc,    // (8, 2048, 2)
    const float* __restrict__ cls,    // (8, 2048, 5)
    const float* __restrict__ defs,   // (2048, 2)
    float* __restrict__ out)          // (8, 4, 2048, 3)
{
#pragma clang fp contract(off)
    const int tid  = threadIdx.x;
    const int lane = tid & 63;
    const int wid  = tid >> 6;
    const int bc   = blockIdx.x;   // 0..31
    const int b    = bc >> 2;
    const int c    = bc & 3;       // softmax component c+1

    // Compacted valid candidates (ordered by original index via block scan)
    __shared__ float         csc[N_ANCHORS];
    __shared__ float         cbs[N_ANCHORS];
    __shared__ float         cbe[N_ANCHORS];
    __shared__ int           cid[N_ANCHORS];
    __shared__ unsigned char kflag[N_ANCHORS];
    __shared__ int           s_wsum[4];
    __shared__ int           s_woff[4];
    __shared__ int           s_V;

    // ---- Phase 1: softmax + decode for 8 CONSECUTIVE anchors per thread ----
    // (consecutive ownership => ordered compaction => compacted pos order
    //  == original-index order, which is the stable-argsort tie-break)
    const int base = tid * 8;
    float sc8[8], bs8[8], be8[8];
    int vmask = 0, cnt = 0;
#pragma unroll
    for (int k = 0; k < 8; ++k) {
        const int n = base + k;
        const float* cp = cls + ((size_t)b * N_ANCHORS + n) * 5;
        float x0 = cp[0], x1 = cp[1], x2 = cp[2], x3 = cp[3], x4 = cp[4];
        float m  = fmaxf(fmaxf(fmaxf(fmaxf(x0, x1), x2), x3), x4);
        float e0 = expf(x0 - m), e1 = expf(x1 - m), e2 = expf(x2 - m),
              e3 = expf(x3 - m), e4 = expf(x4 - m);
        float sum = e0 + e1 + e2 + e3 + e4;
        float ec  = (c == 0) ? e1 : (c == 1) ? e2 : (c == 2) ? e3 : e4;
        float score = ec / sum;

        const float* lp = loc + ((size_t)b * N_ANCHORS + n) * 2;
        float l0 = lp[0], l1 = lp[1];
        float d0 = defs[n * 2 + 0], d1 = defs[n * 2 + 1];
        float cc = d0 + l0 * d1;
        float w  = d1 * expf(l1);
        sc8[k] = score;
        bs8[k] = cc - 0.5f * w;
        be8[k] = cc + 0.5f * w;
        if (score > THRESH) { vmask |= (1 << k); cnt++; }
    }
    for (int i = tid; i < N_ANCHORS; i += BLOCK) kflag[i] = 0;

    // ---- block exclusive scan of cnt (ordered compaction) ----
    int inc = cnt;
    for (int d = 1; d < 64; d <<= 1) {
        int v = __shfl_up(inc, d);
        if (lane >= d) inc += v;
    }
    if (lane == 63) s_wsum[wid] = inc;
    __syncthreads();
    if (tid == 0) {
        int off = 0;
        for (int w = 0; w < 4; ++w) { s_woff[w] = off; off += s_wsum[w]; }
        s_V = off;
    }
    __syncthreads();
    int off = s_woff[wid] + (inc - cnt);
#pragma unroll
    for (int k = 0; k < 8; ++k) {
        if (vmask & (1 << k)) {
            csc[off] = sc8[k];
            cbs[off] = bs8[k];
            cbe[off] = be8[k];
            cid[off] = base + k;
            off++;
        }
    }
    __syncthreads();
    const int V = s_V;
    float* const outb = out + (size_t)bc * N_ANCHORS * 3;

    if (tid < 64) {
        // ---- Phase 2 (wave 0 only): barrier-free greedy NMS ----
        // alive bitmask distributed: lane i owns chunk i (positions 64i..64i+63)
        const int W = (V + 63) >> 6;
        unsigned long long alive = 0ull;
        if (lane < W) {
            int rem = V - (lane << 6);
            alive = (rem >= 64) ? ~0ull : ((1ull << rem) - 1ull);
        }

        // initial argmax over all valid
        float bscore = -INFINITY; int bpos = -1;
        for (int it = 0; it < W; ++it) {
            int j = (it << 6) + lane;
            if (j < V) {
                float sc = csc[j];
                if (sc > bscore) { bscore = sc; bpos = j; }  // j increasing: ties keep lower pos
            }
        }
        for (int d = 32; d; d >>= 1) {
            float os = __shfl_xor(bscore, d);
            int   op = __shfl_xor(bpos, d);
            if (op >= 0 && (os > bscore || (os == bscore && (bpos < 0 || op < bpos))))
                { bscore = os; bpos = op; }
        }

        while (bpos >= 0) {
            const int s = bpos;
            if (lane == 0) kflag[s] = 1;
            const float bs_s  = cbs[s];
            const float be_s  = cbe[s];
            const float len_s = be_s - bs_s;

            // fused suppress + next-argmax
            float nscore = -INFINITY; int npos = -1;
            for (int it = 0; it < W; ++it) {
                unsigned long long w = __shfl(alive, it);
                int j = (it << 6) + lane;
                bool act = ((w >> lane) & 1ull) != 0ull;   // implies j < V
                int ji = j & (N_ANCHORS - 1);              // safe LDS index
                float bsj = cbs[ji], bej = cbe[ji];
                float inter = fminf(be_s, bej) - fmaxf(bs_s, bsj);
                inter = fmaxf(inter, 0.0f);
                float uni = len_s + (bej - bsj) - inter;
                float iou = inter / fmaxf(uni, 1e-12f);
                bool sup = act && ((iou > OVERLAP) || (j == s));
                unsigned long long supm = __ballot(sup);
                if (lane == it) alive &= ~supm;
                if (act && !sup) {
                    float sc = csc[ji];
                    if (sc > nscore || (sc == nscore && j < npos)) { nscore = sc; npos = j; }
                }
            }
            for (int d = 32; d; d >>= 1) {
                float os = __shfl_xor(nscore, d);
                int   op = __shfl_xor(npos, d);
                if (op >= 0 && (os > nscore || (os == nscore && (npos < 0 || op < npos))))
                    { nscore = os; npos = op; }
            }
            bscore = nscore; bpos = npos;
        }
    } else {
        // ---- waves 1-3: zero the output concurrently with NMS ----
        for (int i = tid - 64; i < N_ANCHORS * 3; i += (BLOCK - 64))
            outb[i] = 0.0f;
    }
    __syncthreads();

    // ---- Phase 3: scatter kept boxes (in_range applied at output only) ----
    for (int p = tid; p < V; p += BLOCK) {
        if (kflag[p]) {
            float bsv = cbs[p], bev = cbe[p];
            if (bsv > -10.0f && bev < 10.0f) {
                int n = cid[p];
                float* o = outb + (size_t)n * 3;
                o[0] = bsv;
                o[1] = bev;
                o[2] = csc[p];
            }
        }
    }
}

extern "C" void kernel_launch(void* const* d_in, const int* in_sizes, int n_in,
                              void* d_out, int out_size, void* d_ws, size_t ws_size,
                              hipStream_t stream) {
    const float* loc  = (const float*)d_in[0];  // localizations (8,2048,2)
    const float* cls  = (const float*)d_in[1];  // classifications (8,2048,5)
    const float* defs = (const float*)d_in[2];  // localizations_default (2048,2)
    float* out = (float*)d_out;                 // (8,4,2048,3) fp32
    det_kernel<<<32, BLOCK, 0, stream>>>(loc, cls, defs, out);
}

// Round 3
// 199.037 us; speedup vs baseline: 2.6278x; 2.6278x over previous
//
#include <hip/hip_runtime.h>
#include <math.h>

#define N_ANCHORS 2048
#define BLOCK 256
#define THRESH 0.3f
#define OVERLAP 0.5f

__global__ __launch_bounds__(BLOCK) void det_kernel(
    const float* __restrict__ loc,    // (8, 2048, 2)
    const float* __restrict__ cls,    // (8, 2048, 5)
    const float* __restrict__ defs,   // (2048, 2)
    float* __restrict__ out)          // (8, 4, 2048, 3)
{
#pragma clang fp contract(off)
    const int tid  = threadIdx.x;
    const int lane = tid & 63;
    const int wid  = tid >> 6;
    const int bc   = blockIdx.x;   // 0..31
    const int b    = bc >> 2;
    const int c    = bc & 3;       // softmax component c+1

    // LDS ~61.5 KB total (must stay under 64 KB)
    __shared__ float         csc[N_ANCHORS];   // score, compacted (index order)
    __shared__ float2        cbx[N_ANCHORS];   // box,   compacted (index order)
    __shared__ int           cid[N_ANCHORS];   // anchor id, compacted
    __shared__ float2        sbox[N_ANCHORS];  // box, score-sorted order
    __shared__ int           sinv[N_ANCHORS];  // sorted pos -> compacted pos
    __shared__ unsigned char sup[N_ANCHORS];   // suppressed flag (sorted pos)
    __shared__ unsigned char kfl[N_ANCHORS];   // kept flag (sorted pos)
    __shared__ int           s_wsum[4];
    __shared__ int           s_woff[4];
    __shared__ int           s_V;
    __shared__ unsigned long long s_km;

    // ---- Phase 1: softmax + decode, 8 CONSECUTIVE anchors per thread ----
    // (consecutive ownership => ordered compaction => compacted order ==
    //  original-index order == stable-argsort tie-break order)
    const int base = tid * 8;
    float sc8[8], bs8[8], be8[8];
    int vmask = 0, cnt = 0;
#pragma unroll
    for (int k = 0; k < 8; ++k) {
        const int n = base + k;
        const float* cp = cls + ((size_t)b * N_ANCHORS + n) * 5;
        float x0 = cp[0], x1 = cp[1], x2 = cp[2], x3 = cp[3], x4 = cp[4];
        float m  = fmaxf(fmaxf(fmaxf(fmaxf(x0, x1), x2), x3), x4);
        float e0 = expf(x0 - m), e1 = expf(x1 - m), e2 = expf(x2 - m),
              e3 = expf(x3 - m), e4 = expf(x4 - m);
        float sum = e0 + e1 + e2 + e3 + e4;
        float ec  = (c == 0) ? e1 : (c == 1) ? e2 : (c == 2) ? e3 : e4;
        float score = ec / sum;

        const float* lp = loc + ((size_t)b * N_ANCHORS + n) * 2;
        float l0 = lp[0], l1 = lp[1];
        float d0 = defs[n * 2 + 0], d1 = defs[n * 2 + 1];
        float cc = d0 + l0 * d1;
        float w  = d1 * expf(l1);
        sc8[k] = score;
        bs8[k] = cc - 0.5f * w;
        be8[k] = cc + 0.5f * w;
        if (score > THRESH) { vmask |= (1 << k); cnt++; }
    }
    for (int i = tid; i < N_ANCHORS; i += BLOCK) { sup[i] = 0; kfl[i] = 0; }

    // zero-fill output early (fire-and-forget; barriers below drain vmcnt
    // before the kept-scatter at the end)
    float* const outb = out + (size_t)bc * N_ANCHORS * 3;
    {
        float4 z4 = make_float4(0.f, 0.f, 0.f, 0.f);
        float4* ob4 = (float4*)outb;
        for (int i = tid; i < (N_ANCHORS * 3) / 4; i += BLOCK) ob4[i] = z4;
    }

    // ---- ordered compaction via block exclusive scan ----
    int inc = cnt;
    for (int d = 1; d < 64; d <<= 1) {
        int v = __shfl_up(inc, d);
        if (lane >= d) inc += v;
    }
    if (lane == 63) s_wsum[wid] = inc;
    __syncthreads();
    if (tid == 0) {
        int off = 0;
        for (int w = 0; w < 4; ++w) { s_woff[w] = off; off += s_wsum[w]; }
        s_V = off;
    }
    __syncthreads();
    int off = s_woff[wid] + (inc - cnt);
#pragma unroll
    for (int k = 0; k < 8; ++k) {
        if (vmask & (1 << k)) {
            csc[off] = sc8[k];
            cbx[off] = make_float2(bs8[k], be8[k]);
            cid[off] = base + k;
            off++;
        }
    }
    __syncthreads();
    const int V = s_V;

    // ---- Phase 2: counting rank (score desc, compacted-pos asc on ties) ----
    // Strict total order => scatter is a permutation. Equals stable
    // argsort(-masked) restricted to valid entries.
    for (int p = tid; p < V; p += BLOCK) {
        float s = csc[p];
        int r = 0;
        for (int i = 0; i < V; ++i) {
            float si = csc[i];                       // LDS broadcast
            r += ((si > s) || (si == s && i < p)) ? 1 : 0;
        }
        sinv[r] = p;
        sbox[r] = cbx[p];
    }
    __syncthreads();

    // ---- Phase 3: chunked bitmask greedy NMS (exact) ----
    const int W = (V + 63) >> 6;
    for (int t = 0; t < W; ++t) {
        const int q0 = t << 6;
        if (wid == 0) {
            const int q = q0 + lane;
            const bool act = (q < V);
            float2 mybox = sbox[act ? q : 0];
            float  mylen = mybox.y - mybox.x;
            bool   pre   = act && !sup[q];

            // in-chunk suppression mask: bit i set if chunk box i (i<lane)
            // suppresses me
            unsigned long long supmask = 0ull;
            for (int i = 0; i < 64; ++i) {
                int qi = q0 + i;
                float2 bi = sbox[qi < V ? qi : 0];   // broadcast read
                float inter = fminf(mybox.y, bi.y) - fmaxf(mybox.x, bi.x);
                inter = fmaxf(inter, 0.0f);
                float uni = (bi.y - bi.x) + mylen - inter;
                float iou = inter / fmaxf(uni, 1e-12f);
                if ((iou > OVERLAP) && (i < lane)) supmask |= (1ull << i);
            }

            // greedy resolve: ~a few cycles per kept box
            unsigned long long cand = __ballot(pre);
            unsigned long long kept = 0ull;
            while (cand) {
                int i = __builtin_ctzll(cand);
                kept |= (1ull << i);
                unsigned long long supn = __ballot(((supmask >> i) & 1ull) != 0ull);
                cand &= ~(supn | (1ull << i));
            }
            if (act) kfl[q] = (unsigned char)((kept >> lane) & 1ull);
            if (lane == 0) s_km = kept;
        }
        __syncthreads();

        // all 4 waves: apply chunk t's kept boxes to later sorted positions
        unsigned long long km = s_km;
        if (km) {
            for (int qb = q0 + 64; qb < V; qb += BLOCK) {
                int q2 = qb + tid;
                if (q2 < V && !sup[q2]) {
                    float2 mb = sbox[q2];
                    float  ml = mb.y - mb.x;
                    unsigned long long m = km;
                    bool sflag = false;
                    while (m) {
                        int i = __builtin_ctzll(m);
                        m &= m - 1ull;
                        float2 bi = sbox[q0 + i];    // broadcast read
                        float inter = fminf(mb.y, bi.y) - fmaxf(mb.x, bi.x);
                        inter = fmaxf(inter, 0.0f);
                        float uni = (bi.y - bi.x) + ml - inter;
                        float iou = inter / fmaxf(uni, 1e-12f);
                        sflag |= (iou > OVERLAP);
                    }
                    if (sflag) sup[q2] = 1;
                }
            }
        }
        __syncthreads();
    }

    // ---- Phase 4: scatter kept boxes (in_range applied at output only) ----
    for (int r = tid; r < V; r += BLOCK) {
        if (kfl[r]) {
            float2 bx = sbox[r];
            if (bx.x > -10.0f && bx.y < 10.0f) {
                int p = sinv[r];
                int n = cid[p];
                float* o = outb + (size_t)n * 3;
                o[0] = bx.x;
                o[1] = bx.y;
                o[2] = csc[p];
            }
        }
    }
}

extern "C" void kernel_launch(void* const* d_in, const int* in_sizes, int n_in,
                              void* d_out, int out_size, void* d_ws, size_t ws_size,
                              hipStream_t stream) {
    const float* loc  = (const float*)d_in[0];  // localizations (8,2048,2)
    const float* cls  = (const float*)d_in[1];  // classifications (8,2048,5)
    const float* defs = (const float*)d_in[2];  // localizations_default (2048,2)
    float* out = (float*)d_out;                 // (8,4,2048,3) fp32
    det_kernel<<<32, BLOCK, 0, stream>>>(loc, cls, defs, out);
}